// Round 1
// baseline (173.122 us; speedup 1.0000x reference)
//
#include <hip/hip_runtime.h>
#include <stdint.h>

typedef __attribute__((ext_vector_type(8))) short short8;
typedef __attribute__((ext_vector_type(4))) short short4v;
typedef __attribute__((ext_vector_type(4))) float float4v;

__device__ __forceinline__ short f2bf(float f) {
    union { float f; uint32_t u; } v; v.f = f;
    uint32_t u = v.u;
    uint32_t r = (u + 0x7fffu + ((u >> 16) & 1u)) >> 16;
    return (short)r;
}

// ---------------- conversion kernels ----------------

__global__ __launch_bounds__(256) void cvt_bf16_kernel(const float* __restrict__ in,
                                                       short* __restrict__ out, int n) {
    int i = (blockIdx.x * 256 + threadIdx.x) * 4;
    if (i < n) {
        float4 v = *(const float4*)(in + i);
        short4v o;
        o.x = f2bf(v.x); o.y = f2bf(v.y); o.z = f2bf(v.z); o.w = f2bf(v.w);
        *(short4v*)(out + i) = o;
    }
}

// out[n*256 + k] = bf16(in[k*N + n]);  K fixed at 256
__global__ __launch_bounds__(256) void cvtT_kernel(const float* __restrict__ in,
                                                   short* __restrict__ out, int N, int total) {
    int idx = blockIdx.x * 256 + threadIdx.x;
    if (idx < total) {
        int n = idx >> 8, k = idx & 255;
        out[idx] = f2bf(in[k * N + n]);
    }
}

// ---------------- GEMM: C = A(Mx256) * Bt(Nx256)^T + bias ----------------
// MODE 0: write bf16 split into Q/K/V (B,H,N,D).  MODE 1: write fp32 to outP.

template<int MODE>
__global__ __launch_bounds__(256) void gemm_kernel(
    const short* __restrict__ A, const short* __restrict__ Bt,
    const float* __restrict__ bias,
    short* __restrict__ outQ, short* __restrict__ outK, short* __restrict__ outV,
    float* __restrict__ outP)
{
    const int K = 256;
    int m0 = blockIdx.x * 64;
    int n0 = blockIdx.y * 64;
    int tid = threadIdx.x;
    int wave = tid >> 6, lane = tid & 63, quad = lane >> 4, lc = lane & 15;

    __shared__ __align__(16) short As[64 * 48];
    __shared__ __align__(16) short Bs[64 * 48];

    float4v acc[4];
    #pragma unroll
    for (int t = 0; t < 4; ++t) acc[t] = (float4v){0.f, 0.f, 0.f, 0.f};

    int srow = tid >> 2, sseg = tid & 3;

    for (int c = 0; c < K; c += 32) {
        __syncthreads();
        *(short8*)(&As[srow * 48 + sseg * 8]) =
            *(const short8*)(A + (size_t)(m0 + srow) * K + c + sseg * 8);
        *(short8*)(&Bs[srow * 48 + sseg * 8]) =
            *(const short8*)(Bt + (size_t)(n0 + srow) * K + c + sseg * 8);
        __syncthreads();

        short8 af = *(short8*)(&As[(wave * 16 + lc) * 48 + quad * 8]);
        #pragma unroll
        for (int t = 0; t < 4; ++t) {
            short8 bf = *(short8*)(&Bs[(t * 16 + lc) * 48 + quad * 8]);
            acc[t] = __builtin_amdgcn_mfma_f32_16x16x32_bf16(af, bf, acc[t], 0, 0, 0);
        }
    }

    #pragma unroll
    for (int t = 0; t < 4; ++t) {
        int cg = n0 + t * 16 + lc;
        float bv = bias[cg];
        #pragma unroll
        for (int r = 0; r < 4; ++r) {
            int rg = m0 + wave * 16 + quad * 4 + r;
            float val = acc[t][r] + bv;
            if (MODE == 0) {
                int s = cg >> 8, rem = cg & 255, h = rem >> 4, d = rem & 15;
                int b = rg >> 11, n = rg & 2047;
                short* dst = (s == 0) ? outQ : ((s == 1) ? outK : outV);
                dst[((((size_t)b * 16 + h) * 2048 + n) << 4) + d] = f2bf(val);
            } else {
                outP[(size_t)rg * 256 + cg] = val;
            }
        }
    }
}

// ---------------- flash attention (no-max softmax, MFMA row-sum) ----------------
// grid: (N/64, B*H), 256 threads (4 waves), wave w handles q rows qbase+w*16..+16.

__global__ __launch_bounds__(256) void attn_kernel(
    const short* __restrict__ Q, const short* __restrict__ Kp, const short* __restrict__ V,
    short* __restrict__ Out)
{
    const int N = 2048;
    int bh = blockIdx.y;
    int b = bh >> 4, h = bh & 15;
    int qbase = blockIdx.x * 64;
    int tid = threadIdx.x;
    int wave = tid >> 6, lane = tid & 63, quad = lane >> 4, lc = lane & 15;

    const short* Qh = Q + (size_t)bh * N * 16;
    const short* Kh = Kp + (size_t)bh * N * 16;
    const short* Vh = V + (size_t)bh * N * 16;

    // key permutation sigma(j') = (j'&3)*16 + (j'>>2), applied consistently to P and V
    __shared__ __align__(16) short Vt[16 * 72];      // Vt[d*72 + j'] = V[c + sigma(j')][d]
    __shared__ __align__(16) short Pb[4][16 * 72];   // per-wave P tile, [row*72 + j']

    short8 qf = {0, 0, 0, 0, 0, 0, 0, 0};
    if (quad < 2)
        qf = *(const short8*)(Qh + (size_t)(qbase + wave * 16 + lc) * 16 + quad * 8);

    short8 ones;
    #pragma unroll
    for (int j = 0; j < 8; ++j) ones[j] = (short)0x3F80;  // bf16 1.0

    float4v Oacc = {0.f, 0.f, 0.f, 0.f};
    float4v Lacc = {0.f, 0.f, 0.f, 0.f};

    int sd = tid & 15, sa = tid >> 4;   // V staging assignment

    for (int c = 0; c < N; c += 64) {
        __syncthreads();
        {   // stage V chunk transposed + permuted: j' = sa*4 + tt -> key c + tt*16 + sa
            short4v pack;
            pack.x = Vh[(size_t)(c + sa) * 16 + sd];
            pack.y = Vh[(size_t)(c + sa + 16) * 16 + sd];
            pack.z = Vh[(size_t)(c + sa + 32) * 16 + sd];
            pack.w = Vh[(size_t)(c + sa + 48) * 16 + sd];
            *(short4v*)(&Vt[sd * 72 + sa * 4]) = pack;
        }
        __syncthreads();

        // S = Q K^T for 64 keys (4 tiles of 16), D=16 zero-padded to K=32
        float4v S[4];
        #pragma unroll
        for (int t = 0; t < 4; ++t) {
            short8 kf = {0, 0, 0, 0, 0, 0, 0, 0};
            if (quad < 2)
                kf = *(const short8*)(Kh + (size_t)(c + t * 16 + lc) * 16 + quad * 8);
            float4v z = {0.f, 0.f, 0.f, 0.f};
            S[t] = __builtin_amdgcn_mfma_f32_16x16x32_bf16(qf, kf, z, 0, 0, 0);
        }

        // P = exp(S) (no max subtraction: logits bounded, fp32/bf16 range is ample).
        // C-layout (row=quad*4+r, col=t*16+lc) -> Pb at j' = lc*4 + t (sigma(j')=t*16+lc)
        #pragma unroll
        for (int r = 0; r < 4; ++r) {
            short4v p;
            p.x = f2bf(__expf(S[0][r]));
            p.y = f2bf(__expf(S[1][r]));
            p.z = f2bf(__expf(S[2][r]));
            p.w = f2bf(__expf(S[3][r]));
            *(short4v*)(&Pb[wave][(quad * 4 + r) * 72 + lc * 4]) = p;
        }

        // O += P*V ; L += P*1  (both in C-layout, contraction over permuted keys)
        #pragma unroll
        for (int mf = 0; mf < 2; ++mf) {
            short8 pf = *(short8*)(&Pb[wave][lc * 72 + mf * 32 + quad * 8]);
            short8 vf = *(short8*)(&Vt[lc * 72 + mf * 32 + quad * 8]);
            Oacc = __builtin_amdgcn_mfma_f32_16x16x32_bf16(pf, vf, Oacc, 0, 0, 0);
            Lacc = __builtin_amdgcn_mfma_f32_16x16x32_bf16(pf, ones, Lacc, 0, 0, 0);
        }
    }

    #pragma unroll
    for (int r = 0; r < 4; ++r) {
        int n = qbase + wave * 16 + quad * 4 + r;
        float o = Oacc[r] / Lacc[r];
        Out[((size_t)(b * 2048 + n)) * 256 + h * 16 + lc] = f2bf(o);
    }
}

// ---------------- launcher ----------------

extern "C" void kernel_launch(void* const* d_in, const int* in_sizes, int n_in,
                              void* d_out, int out_size, void* d_ws, size_t ws_size,
                              hipStream_t stream) {
    const float* x      = (const float*)d_in[0];
    const float* w_qkv  = (const float*)d_in[1];
    const float* b_qkv  = (const float*)d_in[2];
    const float* w_proj = (const float*)d_in[3];
    const float* b_proj = (const float*)d_in[4];
    float* out = (float*)d_out;

    short* xb     = (short*)d_ws;          // 8192*256
    short* wqkvT  = xb + 2097152;          // 768*256
    short* wprojT = wqkvT + 196608;        // 256*256
    short* Qb     = wprojT + 65536;        // 4*16*2048*16
    short* Kb     = Qb + 2097152;
    short* Vb     = Kb + 2097152;
    short* Ab     = Vb + 2097152;          // 8192*256 attention output

    cvt_bf16_kernel<<<2048, 256, 0, stream>>>(x, xb, 2097152);
    cvtT_kernel<<<768, 256, 0, stream>>>(w_qkv, wqkvT, 768, 196608);
    cvtT_kernel<<<256, 256, 0, stream>>>(w_proj, wprojT, 256, 65536);

    gemm_kernel<0><<<dim3(128, 12), 256, 0, stream>>>(xb, wqkvT, b_qkv, Qb, Kb, Vb, nullptr);

    attn_kernel<<<dim3(32, 64), 256, 0, stream>>>(Qb, Kb, Vb, Ab);

    gemm_kernel<1><<<dim3(128, 4), 256, 0, stream>>>(Ab, wprojT, b_proj,
                                                     nullptr, nullptr, nullptr, out);
}

// Round 2
// 164.861 us; speedup vs baseline: 1.0501x; 1.0501x over previous
//
#include <hip/hip_runtime.h>
#include <stdint.h>

typedef __attribute__((ext_vector_type(8))) short short8;
typedef __attribute__((ext_vector_type(4))) short short4v;
typedef __attribute__((ext_vector_type(4))) float float4v;

__device__ __forceinline__ short f2bf(float f) {
    union { float f; uint32_t u; } v; v.f = f;
    uint32_t u = v.u;
    uint32_t r = (u + 0x7fffu + ((u >> 16) & 1u)) >> 16;
    return (short)r;
}

// packed 2x fp32 -> 2x bf16 in one dword (low = first arg)
#if __has_builtin(__builtin_amdgcn_cvt_pk_bf16_f32)
typedef __bf16 bf16x2_t __attribute__((ext_vector_type(2)));
__device__ __forceinline__ uint32_t cvt_pk2(float a, float b) {
    union { bf16x2_t v; uint32_t u; } c;
    c.v = __builtin_amdgcn_cvt_pk_bf16_f32(a, b);
    return c.u;
}
#else
__device__ __forceinline__ uint32_t cvt_pk2(float a, float b) {
    union { float f; uint32_t u; } x, y; x.f = a; y.f = b;
    return ((x.u + 0x8000u) >> 16) | ((y.u + 0x8000u) & 0xFFFF0000u);
}
#endif

// ---------------- conversion kernels ----------------

__global__ __launch_bounds__(256) void cvt_bf16_kernel(const float* __restrict__ in,
                                                       short* __restrict__ out, int n) {
    int i = (blockIdx.x * 256 + threadIdx.x) * 4;
    if (i < n) {
        float4 v = *(const float4*)(in + i);
        short4v o;
        o.x = f2bf(v.x); o.y = f2bf(v.y); o.z = f2bf(v.z); o.w = f2bf(v.w);
        *(short4v*)(out + i) = o;
    }
}

// out[n*256 + k] = bf16(in[k*N + n]);  K fixed at 256
__global__ __launch_bounds__(256) void cvtT_kernel(const float* __restrict__ in,
                                                   short* __restrict__ out, int N, int total) {
    int idx = blockIdx.x * 256 + threadIdx.x;
    if (idx < total) {
        int n = idx >> 8, k = idx & 255;
        out[idx] = f2bf(in[k * N + n]);
    }
}

// ---------------- GEMM: C = A(Mx256) * Bt(Nx256)^T + bias ----------------
// MODE 0: write bf16 split into Q/K/V (B,H,N,D); Q pre-scaled by log2(e) so
//         attention can use exp2 directly.  MODE 1: write fp32 to outP.

template<int MODE>
__global__ __launch_bounds__(256) void gemm_kernel(
    const short* __restrict__ A, const short* __restrict__ Bt,
    const float* __restrict__ bias,
    short* __restrict__ outQ, short* __restrict__ outK, short* __restrict__ outV,
    float* __restrict__ outP)
{
    const int K = 256;
    int m0 = blockIdx.x * 64;
    int n0 = blockIdx.y * 64;
    int tid = threadIdx.x;
    int wave = tid >> 6, lane = tid & 63, quad = lane >> 4, lc = lane & 15;

    __shared__ __align__(16) short As[64 * 48];
    __shared__ __align__(16) short Bs[64 * 48];

    float4v acc[4];
    #pragma unroll
    for (int t = 0; t < 4; ++t) acc[t] = (float4v){0.f, 0.f, 0.f, 0.f};

    int srow = tid >> 2, sseg = tid & 3;

    for (int c = 0; c < K; c += 32) {
        __syncthreads();
        *(short8*)(&As[srow * 48 + sseg * 8]) =
            *(const short8*)(A + (size_t)(m0 + srow) * K + c + sseg * 8);
        *(short8*)(&Bs[srow * 48 + sseg * 8]) =
            *(const short8*)(Bt + (size_t)(n0 + srow) * K + c + sseg * 8);
        __syncthreads();

        short8 af = *(short8*)(&As[(wave * 16 + lc) * 48 + quad * 8]);
        #pragma unroll
        for (int t = 0; t < 4; ++t) {
            short8 bf = *(short8*)(&Bs[(t * 16 + lc) * 48 + quad * 8]);
            acc[t] = __builtin_amdgcn_mfma_f32_16x16x32_bf16(af, bf, acc[t], 0, 0, 0);
        }
    }

    #pragma unroll
    for (int t = 0; t < 4; ++t) {
        int cg = n0 + t * 16 + lc;
        float bv = bias[cg];
        #pragma unroll
        for (int r = 0; r < 4; ++r) {
            int rg = m0 + wave * 16 + quad * 4 + r;
            float val = acc[t][r] + bv;
            if (MODE == 0) {
                int s = cg >> 8, rem = cg & 255, h = rem >> 4, d = rem & 15;
                int b = rg >> 11, n = rg & 2047;
                if (s == 0) val *= 1.4426950408889634f;  // fold log2(e) into Q
                short* dst = (s == 0) ? outQ : ((s == 1) ? outK : outV);
                dst[((((size_t)b * 16 + h) * 2048 + n) << 4) + d] = f2bf(val);
            } else {
                outP[(size_t)rg * 256 + cg] = val;
            }
        }
    }
}

// ---------------- flash attention (no-max softmax, MFMA row-sum) ----------------
// grid: (N/64, B*H), 256 threads (4 waves), wave w handles q rows qbase+w*16..+16.

__global__ __launch_bounds__(256) void attn_kernel(
    const short* __restrict__ Q, const short* __restrict__ Kp, const short* __restrict__ V,
    short* __restrict__ Out)
{
    const int N = 2048;
    int bh = blockIdx.y;
    int b = bh >> 4, h = bh & 15;
    int qbase = blockIdx.x * 64;
    int tid = threadIdx.x;
    int wave = tid >> 6, lane = tid & 63, quad = lane >> 4, lc = lane & 15;

    const short* Qh = Q + (size_t)bh * N * 16;
    const short* Kh = Kp + (size_t)bh * N * 16;
    const short* Vh = V + (size_t)bh * N * 16;

    // key permutation sigma(j') = (j'&3)*16 + (j'>>2), applied consistently to P and V
    __shared__ __align__(16) short Vt[16 * 72];      // Vt[d*72 + j'] = V[c + sigma(j')][d]
    __shared__ __align__(16) short Pb[4][16 * 72];   // per-wave P tile, [row*72 + j']

    short8 qf = {0, 0, 0, 0, 0, 0, 0, 0};
    if (quad < 2)
        qf = *(const short8*)(Qh + (size_t)(qbase + wave * 16 + lc) * 16 + quad * 8);

    short8 ones;
    #pragma unroll
    for (int j = 0; j < 8; ++j) ones[j] = (short)0x3F80;  // bf16 1.0

    float4v Oacc = {0.f, 0.f, 0.f, 0.f};
    float4v Lacc = {0.f, 0.f, 0.f, 0.f};

    int sd = tid & 15, sa = tid >> 4;   // V staging assignment

    for (int c = 0; c < N; c += 64) {
        __syncthreads();
        {   // stage V chunk transposed + permuted: j' = sa*4 + tt -> key c + tt*16 + sa
            short4v pack;
            pack.x = Vh[(size_t)(c + sa) * 16 + sd];
            pack.y = Vh[(size_t)(c + sa + 16) * 16 + sd];
            pack.z = Vh[(size_t)(c + sa + 32) * 16 + sd];
            pack.w = Vh[(size_t)(c + sa + 48) * 16 + sd];
            *(short4v*)(&Vt[sd * 72 + sa * 4]) = pack;
        }
        __syncthreads();

        // S = Q K^T for 64 keys (4 tiles of 16), D=16 zero-padded to K=32
        float4v S[4];
        #pragma unroll
        for (int t = 0; t < 4; ++t) {
            short8 kf = {0, 0, 0, 0, 0, 0, 0, 0};
            if (quad < 2)
                kf = *(const short8*)(Kh + (size_t)(c + t * 16 + lc) * 16 + quad * 8);
            float4v z = {0.f, 0.f, 0.f, 0.f};
            S[t] = __builtin_amdgcn_mfma_f32_16x16x32_bf16(qf, kf, z, 0, 0, 0);
        }

        // P = exp2(S) (Q pre-scaled by log2 e; no max subtraction: logits bounded).
        // C-layout (row=quad*4+r, col=t*16+lc) -> Pb at j' = lc*4 + t (sigma(j')=t*16+lc)
        #pragma unroll
        for (int r = 0; r < 4; ++r) {
            uint32_t u0 = cvt_pk2(__builtin_amdgcn_exp2f(S[0][r]),
                                  __builtin_amdgcn_exp2f(S[1][r]));
            uint32_t u1 = cvt_pk2(__builtin_amdgcn_exp2f(S[2][r]),
                                  __builtin_amdgcn_exp2f(S[3][r]));
            uint2 w; w.x = u0; w.y = u1;
            *(uint2*)(&Pb[wave][(quad * 4 + r) * 72 + lc * 4]) = w;
        }

        // O += P*V ; L += P*1  (both in C-layout, contraction over permuted keys)
        #pragma unroll
        for (int mf = 0; mf < 2; ++mf) {
            short8 pf = *(short8*)(&Pb[wave][lc * 72 + mf * 32 + quad * 8]);
            short8 vf = *(short8*)(&Vt[lc * 72 + mf * 32 + quad * 8]);
            Oacc = __builtin_amdgcn_mfma_f32_16x16x32_bf16(pf, vf, Oacc, 0, 0, 0);
            Lacc = __builtin_amdgcn_mfma_f32_16x16x32_bf16(pf, ones, Lacc, 0, 0, 0);
        }
    }

    #pragma unroll
    for (int r = 0; r < 4; ++r) {
        int n = qbase + wave * 16 + quad * 4 + r;
        float o = Oacc[r] / Lacc[r];
        Out[((size_t)(b * 2048 + n)) * 256 + h * 16 + lc] = f2bf(o);
    }
}

// ---------------- launcher ----------------

extern "C" void kernel_launch(void* const* d_in, const int* in_sizes, int n_in,
                              void* d_out, int out_size, void* d_ws, size_t ws_size,
                              hipStream_t stream) {
    const float* x      = (const float*)d_in[0];
    const float* w_qkv  = (const float*)d_in[1];
    const float* b_qkv  = (const float*)d_in[2];
    const float* w_proj = (const float*)d_in[3];
    const float* b_proj = (const float*)d_in[4];
    float* out = (float*)d_out;

    short* xb     = (short*)d_ws;          // 8192*256
    short* wqkvT  = xb + 2097152;          // 768*256
    short* wprojT = wqkvT + 196608;        // 256*256
    short* Qb     = wprojT + 65536;        // 4*16*2048*16
    short* Kb     = Qb + 2097152;
    short* Vb     = Kb + 2097152;
    short* Ab     = Vb + 2097152;          // 8192*256 attention output

    cvt_bf16_kernel<<<2048, 256, 0, stream>>>(x, xb, 2097152);
    cvtT_kernel<<<768, 256, 0, stream>>>(w_qkv, wqkvT, 768, 196608);
    cvtT_kernel<<<256, 256, 0, stream>>>(w_proj, wprojT, 256, 65536);

    gemm_kernel<0><<<dim3(128, 12), 256, 0, stream>>>(xb, wqkvT, b_qkv, Qb, Kb, Vb, nullptr);

    attn_kernel<<<dim3(32, 64), 256, 0, stream>>>(Qb, Kb, Vb, Ab);

    gemm_kernel<1><<<dim3(128, 4), 256, 0, stream>>>(Ab, wprojT, b_proj,
                                                     nullptr, nullptr, nullptr, out);
}

// Round 4
// 141.224 us; speedup vs baseline: 1.2259x; 1.1674x over previous
//
#include <hip/hip_runtime.h>
#include <stdint.h>

typedef __attribute__((ext_vector_type(8))) short short8;
typedef __attribute__((ext_vector_type(4))) short short4v;
typedef __attribute__((ext_vector_type(4))) float float4v;
typedef __attribute__((ext_vector_type(16))) float float16v;
typedef __attribute__((ext_vector_type(4))) uint32_t uint4v;

__device__ __forceinline__ short f2bf(float f) {
    union { float f; uint32_t u; } v; v.f = f;
    uint32_t u = v.u;
    uint32_t r = (u + 0x7fffu + ((u >> 16) & 1u)) >> 16;
    return (short)r;
}

// packed 2x fp32 -> 2x bf16 in one dword (low = first arg)
#if __has_builtin(__builtin_amdgcn_cvt_pk_bf16_f32)
typedef __bf16 bf16x2_t __attribute__((ext_vector_type(2)));
__device__ __forceinline__ uint32_t cvt_pk2(float a, float b) {
    union { bf16x2_t v; uint32_t u; } c;
    c.v = __builtin_amdgcn_cvt_pk_bf16_f32(a, b);
    return c.u;
}
#else
__device__ __forceinline__ uint32_t cvt_pk2(float a, float b) {
    union { float f; uint32_t u; } x, y; x.f = a; y.f = b;
    return ((x.u + 0x8000u) >> 16) | ((y.u + 0x8000u) & 0xFFFF0000u);
}
#endif

// ---------------- conversion kernels ----------------

__global__ __launch_bounds__(256) void cvt_bf16_kernel(const float* __restrict__ in,
                                                       short* __restrict__ out, int n) {
    int i = (blockIdx.x * 256 + threadIdx.x) * 4;
    if (i < n) {
        float4 v = *(const float4*)(in + i);
        short4v o;
        o.x = f2bf(v.x); o.y = f2bf(v.y); o.z = f2bf(v.z); o.w = f2bf(v.w);
        *(short4v*)(out + i) = o;
    }
}

// out[n*256 + k] = bf16(in[k*N + n]);  K fixed at 256
__global__ __launch_bounds__(256) void cvtT_kernel(const float* __restrict__ in,
                                                   short* __restrict__ out, int N, int total) {
    int idx = blockIdx.x * 256 + threadIdx.x;
    if (idx < total) {
        int n = idx >> 8, k = idx & 255;
        out[idx] = f2bf(in[k * N + n]);
    }
}

// ---------------- GEMM: C = A(Mx256) * Bt(Nx256)^T + bias ----------------

template<int MODE>
__global__ __launch_bounds__(256) void gemm_kernel(
    const short* __restrict__ A, const short* __restrict__ Bt,
    const float* __restrict__ bias,
    short* __restrict__ outQ, short* __restrict__ outK, short* __restrict__ outV,
    float* __restrict__ outP)
{
    const int K = 256;
    int m0 = blockIdx.x * 64;
    int n0 = blockIdx.y * 64;
    int tid = threadIdx.x;
    int wave = tid >> 6, lane = tid & 63, quad = lane >> 4, lc = lane & 15;

    __shared__ __align__(16) short As[64 * 48];
    __shared__ __align__(16) short Bs[64 * 48];

    float4v acc[4];
    #pragma unroll
    for (int t = 0; t < 4; ++t) acc[t] = (float4v){0.f, 0.f, 0.f, 0.f};

    int srow = tid >> 2, sseg = tid & 3;

    for (int c = 0; c < K; c += 32) {
        __syncthreads();
        *(short8*)(&As[srow * 48 + sseg * 8]) =
            *(const short8*)(A + (size_t)(m0 + srow) * K + c + sseg * 8);
        *(short8*)(&Bs[srow * 48 + sseg * 8]) =
            *(const short8*)(Bt + (size_t)(n0 + srow) * K + c + sseg * 8);
        __syncthreads();

        short8 af = *(short8*)(&As[(wave * 16 + lc) * 48 + quad * 8]);
        #pragma unroll
        for (int t = 0; t < 4; ++t) {
            short8 bf = *(short8*)(&Bs[(t * 16 + lc) * 48 + quad * 8]);
            acc[t] = __builtin_amdgcn_mfma_f32_16x16x32_bf16(af, bf, acc[t], 0, 0, 0);
        }
    }

    #pragma unroll
    for (int t = 0; t < 4; ++t) {
        int cg = n0 + t * 16 + lc;
        float bv = bias[cg];
        #pragma unroll
        for (int r = 0; r < 4; ++r) {
            int rg = m0 + wave * 16 + quad * 4 + r;
            float val = acc[t][r] + bv;
            if (MODE == 0) {
                int s = cg >> 8, rem = cg & 255, h = rem >> 4, d = rem & 15;
                int b = rg >> 11, n = rg & 2047;
                if (s == 0) val *= 1.4426950408889634f;  // fold log2(e) into Q
                short* dst = (s == 0) ? outQ : ((s == 1) ? outK : outV);
                dst[((((size_t)b * 16 + h) * 2048 + n) << 4) + d] = f2bf(val);
            } else {
                outP[(size_t)rg * 256 + cg] = val;
            }
        }
    }
}

// ---------------- flash attention, 32x32x16 MFMA, no P round-trip ----------------
// grid: (N/128, B*H), 256 threads (4 waves); wave w owns q rows qbase+w*32..+32.
// S^T = K * Q^T  (C-layout col=q). exp2 in-regs; packed C regs ARE the B-operand
// of O^T = [V^T;1;0] * P^T.  Slot->key map forced by the 32x32 C/D layout:
//   key(s) = (s&0x33) | ((s&4)<<1) | ((s&8)>>1)   (swap bits 2<->3; low 2 bits
// are CONSECUTIVE keys).  Folded into Vt staging.
// L = row 16 of O^T via the ones-row: no separate L MFMA, no LDS for P.

__global__ __launch_bounds__(256) void attn_kernel(
    const short* __restrict__ Q, const short* __restrict__ Kp, const short* __restrict__ V,
    short* __restrict__ Out)
{
    const int N = 2048;
    int bh = blockIdx.y;
    int b = bh >> 4, h = bh & 15;
    int tid = threadIdx.x;
    int wave = tid >> 6, lane = tid & 63;
    int m = lane & 31, hi = lane >> 5;
    int qbase = blockIdx.x * 128 + wave * 32;

    const short* Qh = Q + (size_t)bh * N * 16;
    const short* Kh = Kp + (size_t)bh * N * 16;
    const short* Vh = V + (size_t)bh * N * 16;

    // Vt[d][slot]: 256-key super-chunk; slot s -> key (s>>6)*64 + swap23(s&63)
    __shared__ __align__(16) short Vt[16][264];

    short8 qf = *(const short8*)(Qh + (size_t)(qbase + m) * 16 + hi * 8);

    short8 ones, zeros;
    #pragma unroll
    for (int j = 0; j < 8; ++j) { ones[j] = (short)0x3F80; zeros[j] = 0; }

    float16v Oacc, zf;
    #pragma unroll
    for (int j = 0; j < 16; ++j) { Oacc[j] = 0.f; zf[j] = 0.f; }

    int sd = tid & 15, sa = tid >> 4;   // thread stages slots sa*4..sa*4+3, dim sd
    // slot sa*4+t -> key kb + t, kb = bit-swapped base (bits: sa0->3, sa1->2, sa>>2->4+)
    int kb = ((sa & 1) << 3) | (((sa >> 1) & 1) << 2) | ((sa >> 2) << 4);

    for (int sc = 0; sc < N; sc += 256) {
        __syncthreads();
        #pragma unroll
        for (int cc = 0; cc < 4; ++cc) {
            const short* vp = Vh + (size_t)(sc + cc * 64 + kb) * 16 + sd;
            short4v pack;
            pack.x = vp[0]; pack.y = vp[16]; pack.z = vp[32]; pack.w = vp[48];
            *(short4v*)(&Vt[sd][cc * 64 + sa * 4]) = pack;
        }
        __syncthreads();

        #pragma unroll
        for (int it = 0; it < 4; ++it) {
            int c = sc + it * 64;
            short8 kf1 = *(const short8*)(Kh + (size_t)(c + m) * 16 + hi * 8);
            short8 kf2 = *(const short8*)(Kh + (size_t)(c + 32 + m) * 16 + hi * 8);

            float16v S1 = __builtin_amdgcn_mfma_f32_32x32x16_bf16(kf1, qf, zf, 0, 0, 0);
            float16v S2 = __builtin_amdgcn_mfma_f32_32x32x16_bf16(kf2, qf, zf, 0, 0, 0);

            union { uint4v u; short8 s; } pA, pB, pC, pD;
            pA.u = (uint4v){
                cvt_pk2(__builtin_amdgcn_exp2f(S1[0]), __builtin_amdgcn_exp2f(S1[1])),
                cvt_pk2(__builtin_amdgcn_exp2f(S1[2]), __builtin_amdgcn_exp2f(S1[3])),
                cvt_pk2(__builtin_amdgcn_exp2f(S1[4]), __builtin_amdgcn_exp2f(S1[5])),
                cvt_pk2(__builtin_amdgcn_exp2f(S1[6]), __builtin_amdgcn_exp2f(S1[7]))};
            pB.u = (uint4v){
                cvt_pk2(__builtin_amdgcn_exp2f(S1[8]),  __builtin_amdgcn_exp2f(S1[9])),
                cvt_pk2(__builtin_amdgcn_exp2f(S1[10]), __builtin_amdgcn_exp2f(S1[11])),
                cvt_pk2(__builtin_amdgcn_exp2f(S1[12]), __builtin_amdgcn_exp2f(S1[13])),
                cvt_pk2(__builtin_amdgcn_exp2f(S1[14]), __builtin_amdgcn_exp2f(S1[15]))};
            pC.u = (uint4v){
                cvt_pk2(__builtin_amdgcn_exp2f(S2[0]), __builtin_amdgcn_exp2f(S2[1])),
                cvt_pk2(__builtin_amdgcn_exp2f(S2[2]), __builtin_amdgcn_exp2f(S2[3])),
                cvt_pk2(__builtin_amdgcn_exp2f(S2[4]), __builtin_amdgcn_exp2f(S2[5])),
                cvt_pk2(__builtin_amdgcn_exp2f(S2[6]), __builtin_amdgcn_exp2f(S2[7]))};
            pD.u = (uint4v){
                cvt_pk2(__builtin_amdgcn_exp2f(S2[8]),  __builtin_amdgcn_exp2f(S2[9])),
                cvt_pk2(__builtin_amdgcn_exp2f(S2[10]), __builtin_amdgcn_exp2f(S2[11])),
                cvt_pk2(__builtin_amdgcn_exp2f(S2[12]), __builtin_amdgcn_exp2f(S2[13])),
                cvt_pk2(__builtin_amdgcn_exp2f(S2[14]), __builtin_amdgcn_exp2f(S2[15]))};

            #pragma unroll
            for (int p = 0; p < 4; ++p) {
                short8 vf;
                if (m < 16)      vf = *(const short8*)(&Vt[m][it * 64 + p * 16 + hi * 8]);
                else if (m == 16) vf = ones;
                else              vf = zeros;
                short8 pf = (p == 0) ? pA.s : (p == 1) ? pB.s : (p == 2) ? pC.s : pD.s;
                Oacc = __builtin_amdgcn_mfma_f32_32x32x16_bf16(vf, pf, Oacc, 0, 0, 0);
            }
        }
    }

    // epilogue: L = row 16 (reg 8, hi==0 lanes); O[q][d] = Oacc_d / L
    float Lq = __shfl(Oacc[8], m, 64);
    float inv = 1.0f / Lq;
    uint32_t o0 = cvt_pk2(Oacc[0] * inv, Oacc[1] * inv);
    uint32_t o1 = cvt_pk2(Oacc[2] * inv, Oacc[3] * inv);
    uint32_t o2 = cvt_pk2(Oacc[4] * inv, Oacc[5] * inv);
    uint32_t o3 = cvt_pk2(Oacc[6] * inv, Oacc[7] * inv);
    short* row = Out + ((size_t)(b * 2048 + qbase + m)) * 256 + h * 16;
    uint2 w0; w0.x = o0; w0.y = o1;
    uint2 w1; w1.x = o2; w1.y = o3;
    *(uint2*)(row + hi * 4) = w0;
    *(uint2*)(row + 8 + hi * 4) = w1;
}

// ---------------- launcher ----------------

extern "C" void kernel_launch(void* const* d_in, const int* in_sizes, int n_in,
                              void* d_out, int out_size, void* d_ws, size_t ws_size,
                              hipStream_t stream) {
    const float* x      = (const float*)d_in[0];
    const float* w_qkv  = (const float*)d_in[1];
    const float* b_qkv  = (const float*)d_in[2];
    const float* w_proj = (const float*)d_in[3];
    const float* b_proj = (const float*)d_in[4];
    float* out = (float*)d_out;

    short* xb     = (short*)d_ws;          // 8192*256
    short* wqkvT  = xb + 2097152;          // 768*256
    short* wprojT = wqkvT + 196608;        // 256*256
    short* Qb     = wprojT + 65536;        // 4*16*2048*16
    short* Kb     = Qb + 2097152;
    short* Vb     = Kb + 2097152;
    short* Ab     = Vb + 2097152;          // 8192*256 attention output

    cvt_bf16_kernel<<<2048, 256, 0, stream>>>(x, xb, 2097152);
    cvtT_kernel<<<768, 256, 0, stream>>>(w_qkv, wqkvT, 768, 196608);
    cvtT_kernel<<<256, 256, 0, stream>>>(w_proj, wprojT, 256, 65536);

    gemm_kernel<0><<<dim3(128, 12), 256, 0, stream>>>(xb, wqkvT, b_qkv, Qb, Kb, Vb, nullptr);

    attn_kernel<<<dim3(16, 64), 256, 0, stream>>>(Qb, Kb, Vb, Ab);

    gemm_kernel<1><<<dim3(128, 4), 256, 0, stream>>>(Ab, wprojT, b_proj,
                                                     nullptr, nullptr, nullptr, out);
}

// Round 5
// 139.857 us; speedup vs baseline: 1.2379x; 1.0098x over previous
//
#include <hip/hip_runtime.h>
#include <stdint.h>

typedef __attribute__((ext_vector_type(8))) short short8;
typedef __attribute__((ext_vector_type(4))) short short4v;
typedef __attribute__((ext_vector_type(4))) float float4v;
typedef __attribute__((ext_vector_type(16))) float float16v;
typedef __attribute__((ext_vector_type(4))) uint32_t uint4v;

__device__ __forceinline__ short f2bf(float f) {
    union { float f; uint32_t u; } v; v.f = f;
    uint32_t u = v.u;
    uint32_t r = (u + 0x7fffu + ((u >> 16) & 1u)) >> 16;
    return (short)r;
}

// packed 2x fp32 -> 2x bf16 in one dword (low = first arg)
#if __has_builtin(__builtin_amdgcn_cvt_pk_bf16_f32)
typedef __bf16 bf16x2_t __attribute__((ext_vector_type(2)));
__device__ __forceinline__ uint32_t cvt_pk2(float a, float b) {
    union { bf16x2_t v; uint32_t u; } c;
    c.v = __builtin_amdgcn_cvt_pk_bf16_f32(a, b);
    return c.u;
}
#else
__device__ __forceinline__ uint32_t cvt_pk2(float a, float b) {
    union { float f; uint32_t u; } x, y; x.f = a; y.f = b;
    return ((x.u + 0x8000u) >> 16) | ((y.u + 0x8000u) & 0xFFFF0000u);
}
#endif

// ---------------- merged weight transpose-convert ----------------
// wqkvT[n*256+k] = bf16(w_qkv[k*768+n]);  wprojT[n*256+k] = bf16(w_proj[k*256+n])

__global__ __launch_bounds__(256) void cvtW_kernel(const float* __restrict__ wqkv,
                                                   const float* __restrict__ wproj,
                                                   short* __restrict__ outq,
                                                   short* __restrict__ outp) {
    int idx = blockIdx.x * 256 + threadIdx.x;
    if (idx < 196608) {
        int n = idx >> 8, k = idx & 255;
        outq[idx] = f2bf(wqkv[k * 768 + n]);
    } else {
        int i = idx - 196608;
        int n = i >> 8, k = i & 255;
        outp[i] = f2bf(wproj[k * 256 + n]);
    }
}

// ---------------- GEMM: C = A(Mx256) * Bt(Nx256)^T + bias ----------------
// MODE 0: A is fp32 (x), converted to bf16 during LDS staging; outputs split
//         into Q/K/V (B,H,N,D) bf16, Q pre-scaled by log2(e).
// MODE 1: A is bf16; output fp32 to outP.

template<int MODE>
__global__ __launch_bounds__(256) void gemm_kernel(
    const void* __restrict__ Ap, const short* __restrict__ Bt,
    const float* __restrict__ bias,
    short* __restrict__ outQ, short* __restrict__ outK, short* __restrict__ outV,
    float* __restrict__ outP)
{
    const int K = 256;
    int m0 = blockIdx.x * 64;
    int n0 = blockIdx.y * 64;
    int tid = threadIdx.x;
    int wave = tid >> 6, lane = tid & 63, quad = lane >> 4, lc = lane & 15;

    __shared__ __align__(16) short As[64 * 48];
    __shared__ __align__(16) short Bs[64 * 48];

    float4v acc[4];
    #pragma unroll
    for (int t = 0; t < 4; ++t) acc[t] = (float4v){0.f, 0.f, 0.f, 0.f};

    int srow = tid >> 2, sseg = tid & 3;

    for (int c = 0; c < K; c += 32) {
        __syncthreads();
        if (MODE == 0) {
            const float* src = (const float*)Ap + (size_t)(m0 + srow) * K + c + sseg * 8;
            float4 f0 = *(const float4*)src;
            float4 f1 = *(const float4*)(src + 4);
            uint4v u; u.x = cvt_pk2(f0.x, f0.y); u.y = cvt_pk2(f0.z, f0.w);
            u.z = cvt_pk2(f1.x, f1.y); u.w = cvt_pk2(f1.z, f1.w);
            *(uint4v*)(&As[srow * 48 + sseg * 8]) = u;
        } else {
            *(short8*)(&As[srow * 48 + sseg * 8]) =
                *(const short8*)((const short*)Ap + (size_t)(m0 + srow) * K + c + sseg * 8);
        }
        *(short8*)(&Bs[srow * 48 + sseg * 8]) =
            *(const short8*)(Bt + (size_t)(n0 + srow) * K + c + sseg * 8);
        __syncthreads();

        short8 af = *(short8*)(&As[(wave * 16 + lc) * 48 + quad * 8]);
        #pragma unroll
        for (int t = 0; t < 4; ++t) {
            short8 bf = *(short8*)(&Bs[(t * 16 + lc) * 48 + quad * 8]);
            acc[t] = __builtin_amdgcn_mfma_f32_16x16x32_bf16(af, bf, acc[t], 0, 0, 0);
        }
    }

    #pragma unroll
    for (int t = 0; t < 4; ++t) {
        int cg = n0 + t * 16 + lc;
        float bv = bias[cg];
        #pragma unroll
        for (int r = 0; r < 4; ++r) {
            int rg = m0 + wave * 16 + quad * 4 + r;
            float val = acc[t][r] + bv;
            if (MODE == 0) {
                int s = cg >> 8, rem = cg & 255, h = rem >> 4, d = rem & 15;
                int b = rg >> 11, n = rg & 2047;
                if (s == 0) val *= 1.4426950408889634f;  // fold log2(e) into Q
                short* dst = (s == 0) ? outQ : ((s == 1) ? outK : outV);
                dst[((((size_t)b * 16 + h) * 2048 + n) << 4) + d] = f2bf(val);
            } else {
                outP[(size_t)rg * 256 + cg] = val;
            }
        }
    }
}

// ---------------- flash attention, 32x32x16 MFMA, no P round-trip ----------------
// grid: (N/128, B*H), 256 threads (4 waves); wave w owns q rows qbase+w*32..+32.
// S^T = K * Q^T  (C-layout col=q). exp2 in-regs; packed C regs ARE the B-operand
// of O^T = [V^T;1;0] * P^T.  Slot->key map forced by the 32x32 C/D layout:
//   key(s) = (s&0x33) | ((s&4)<<1) | ((s&8)>>1)   (swap bits 2<->3; low 2 bits
// are CONSECUTIVE keys).  Folded into Vt staging.
// Rows 16..31 of the A-operand (ones row for L, zeros) live in LDS as constant
// rows written once -> vf is one unconditional ds_read_b128 (no divergent select).

__global__ __launch_bounds__(256) void attn_kernel(
    const short* __restrict__ Q, const short* __restrict__ Kp, const short* __restrict__ V,
    short* __restrict__ Out)
{
    const int N = 2048;
    int bh = blockIdx.y;
    int b = bh >> 4, h = bh & 15;
    int tid = threadIdx.x;
    int wave = tid >> 6, lane = tid & 63;
    int m = lane & 31, hi = lane >> 5;
    int qbase = blockIdx.x * 128 + wave * 32;

    const short* Qh = Q + (size_t)bh * N * 16;
    const short* Kh = Kp + (size_t)bh * N * 16;
    const short* Vh = V + (size_t)bh * N * 16;

    // rows 0-15: V^T staged per 256-key super-chunk; row 16: ones; 17-31: zeros
    __shared__ __align__(16) short Vt[32][264];

    {   // one-time constant-row init (rows 16..31, cols 0..255)
        int r = 16 + (tid >> 4);
        int c0 = (tid & 15) * 16;
        short fill = (r == 16) ? (short)0x3F80 : (short)0;
        short8 f8;
        #pragma unroll
        for (int j = 0; j < 8; ++j) f8[j] = fill;
        *(short8*)(&Vt[r][c0]) = f8;
        *(short8*)(&Vt[r][c0 + 8]) = f8;
    }

    short8 qf = *(const short8*)(Qh + (size_t)(qbase + m) * 16 + hi * 8);

    float16v Oacc, zf;
    #pragma unroll
    for (int j = 0; j < 16; ++j) { Oacc[j] = 0.f; zf[j] = 0.f; }

    int sd = tid & 15, sa = tid >> 4;   // thread stages slots sa*4..sa*4+3, dim sd
    // slot sa*4+t -> key kb + t, kb = bit-swapped base (bits: sa0->3, sa1->2, sa>>2->4+)
    int kb = ((sa & 1) << 3) | (((sa >> 1) & 1) << 2) | ((sa >> 2) << 4);

    for (int sc = 0; sc < N; sc += 256) {
        __syncthreads();
        #pragma unroll
        for (int cc = 0; cc < 4; ++cc) {
            const short* vp = Vh + (size_t)(sc + cc * 64 + kb) * 16 + sd;
            short4v pack;
            pack.x = vp[0]; pack.y = vp[16]; pack.z = vp[32]; pack.w = vp[48];
            *(short4v*)(&Vt[sd][cc * 64 + sa * 4]) = pack;
        }
        __syncthreads();

        #pragma unroll
        for (int it = 0; it < 4; ++it) {
            int c = sc + it * 64;
            short8 kf1 = *(const short8*)(Kh + (size_t)(c + m) * 16 + hi * 8);
            short8 kf2 = *(const short8*)(Kh + (size_t)(c + 32 + m) * 16 + hi * 8);

            float16v S1 = __builtin_amdgcn_mfma_f32_32x32x16_bf16(kf1, qf, zf, 0, 0, 0);
            float16v S2 = __builtin_amdgcn_mfma_f32_32x32x16_bf16(kf2, qf, zf, 0, 0, 0);

            union { uint4v u; short8 s; } pA, pB, pC, pD;
            pA.u = (uint4v){
                cvt_pk2(__builtin_amdgcn_exp2f(S1[0]), __builtin_amdgcn_exp2f(S1[1])),
                cvt_pk2(__builtin_amdgcn_exp2f(S1[2]), __builtin_amdgcn_exp2f(S1[3])),
                cvt_pk2(__builtin_amdgcn_exp2f(S1[4]), __builtin_amdgcn_exp2f(S1[5])),
                cvt_pk2(__builtin_amdgcn_exp2f(S1[6]), __builtin_amdgcn_exp2f(S1[7]))};
            pB.u = (uint4v){
                cvt_pk2(__builtin_amdgcn_exp2f(S1[8]),  __builtin_amdgcn_exp2f(S1[9])),
                cvt_pk2(__builtin_amdgcn_exp2f(S1[10]), __builtin_amdgcn_exp2f(S1[11])),
                cvt_pk2(__builtin_amdgcn_exp2f(S1[12]), __builtin_amdgcn_exp2f(S1[13])),
                cvt_pk2(__builtin_amdgcn_exp2f(S1[14]), __builtin_amdgcn_exp2f(S1[15]))};
            pC.u = (uint4v){
                cvt_pk2(__builtin_amdgcn_exp2f(S2[0]), __builtin_amdgcn_exp2f(S2[1])),
                cvt_pk2(__builtin_amdgcn_exp2f(S2[2]), __builtin_amdgcn_exp2f(S2[3])),
                cvt_pk2(__builtin_amdgcn_exp2f(S2[4]), __builtin_amdgcn_exp2f(S2[5])),
                cvt_pk2(__builtin_amdgcn_exp2f(S2[6]), __builtin_amdgcn_exp2f(S2[7]))};
            pD.u = (uint4v){
                cvt_pk2(__builtin_amdgcn_exp2f(S2[8]),  __builtin_amdgcn_exp2f(S2[9])),
                cvt_pk2(__builtin_amdgcn_exp2f(S2[10]), __builtin_amdgcn_exp2f(S2[11])),
                cvt_pk2(__builtin_amdgcn_exp2f(S2[12]), __builtin_amdgcn_exp2f(S2[13])),
                cvt_pk2(__builtin_amdgcn_exp2f(S2[14]), __builtin_amdgcn_exp2f(S2[15]))};

            #pragma unroll
            for (int p = 0; p < 4; ++p) {
                short8 vf = *(const short8*)(&Vt[m][it * 64 + p * 16 + hi * 8]);
                short8 pf = (p == 0) ? pA.s : (p == 1) ? pB.s : (p == 2) ? pC.s : pD.s;
                Oacc = __builtin_amdgcn_mfma_f32_32x32x16_bf16(vf, pf, Oacc, 0, 0, 0);
            }
        }
    }

    // epilogue: L = row 16 (reg 8, hi==0 lanes); O[q][d] = Oacc_d / L
    float Lq = __shfl(Oacc[8], m, 64);
    float inv = 1.0f / Lq;
    uint32_t o0 = cvt_pk2(Oacc[0] * inv, Oacc[1] * inv);
    uint32_t o1 = cvt_pk2(Oacc[2] * inv, Oacc[3] * inv);
    uint32_t o2 = cvt_pk2(Oacc[4] * inv, Oacc[5] * inv);
    uint32_t o3 = cvt_pk2(Oacc[6] * inv, Oacc[7] * inv);
    short* row = Out + ((size_t)(b * 2048 + qbase + m)) * 256 + h * 16;
    uint2 w0; w0.x = o0; w0.y = o1;
    uint2 w1; w1.x = o2; w1.y = o3;
    *(uint2*)(row + hi * 4) = w0;
    *(uint2*)(row + 8 + hi * 4) = w1;
}

// ---------------- launcher ----------------

extern "C" void kernel_launch(void* const* d_in, const int* in_sizes, int n_in,
                              void* d_out, int out_size, void* d_ws, size_t ws_size,
                              hipStream_t stream) {
    const float* x      = (const float*)d_in[0];
    const float* w_qkv  = (const float*)d_in[1];
    const float* b_qkv  = (const float*)d_in[2];
    const float* w_proj = (const float*)d_in[3];
    const float* b_proj = (const float*)d_in[4];
    float* out = (float*)d_out;

    short* wqkvT  = (short*)d_ws;          // 768*256
    short* wprojT = wqkvT + 196608;        // 256*256
    short* Qb     = wprojT + 65536;        // 4*16*2048*16
    short* Kb     = Qb + 2097152;
    short* Vb     = Kb + 2097152;
    short* Ab     = Vb + 2097152;          // 8192*256 attention output

    cvtW_kernel<<<1024, 256, 0, stream>>>(w_qkv, w_proj, wqkvT, wprojT);

    gemm_kernel<0><<<dim3(128, 12), 256, 0, stream>>>(x, wqkvT, b_qkv, Qb, Kb, Vb, nullptr);

    attn_kernel<<<dim3(16, 64), 256, 0, stream>>>(Qb, Kb, Vb, Ab);

    gemm_kernel<1><<<dim3(128, 4), 256, 0, stream>>>(Ab, wprojT, b_proj,
                                                     nullptr, nullptr, nullptr, out);
}